// Round 1
// baseline (862.107 us; speedup 1.0000x reference)
//
#include <hip/hip_runtime.h>
#include <math.h>

// Problem constants (from reference): N=500000, NFEAT=64, K=8, HK=64
constexpr int NS  = 500000;
constexpr int NF  = 64;
constexpr int KG  = 8;
constexpr int HKC = 64;

// Kernel 1: w = exp(z) into workspace; zero the A region of d_out.
// (Harness poisons d_out/d_ws to 0xAA before every timed launch.)
__global__ void prep_kernel(const float* __restrict__ z, float* __restrict__ w,
                            float* __restrict__ A) {
    int i = blockIdx.x * blockDim.x + threadIdx.x;
    if (i < KG * HKC * NF) w[i] = expf(z[i]);
    if (i < KG * HKC)      A[i] = 0.0f;
}

// Main kernel: one sample per thread.
// x row lives in VGPRs; w/t addresses are wave-uniform (loop indices only)
// so the compiler can use scalar loads for them.
__global__ __launch_bounds__(256) void monn_kernel(
    const float* __restrict__ x, const float* __restrict__ w,
    const float* __restrict__ t, float* __restrict__ y,
    float* __restrict__ A) {
    int n = blockIdx.x * blockDim.x + threadIdx.x;
    if (n >= NS) return;

    // Load this sample's 64 features into registers (float4 chunks).
    float xr[NF];
    const float* xp = x + (size_t)n * NF;
#pragma unroll
    for (int i = 0; i < NF; i += 4) {
        float4 v = *reinterpret_cast<const float4*>(xp + i);
        xr[i] = v.x; xr[i + 1] = v.y; xr[i + 2] = v.z; xr[i + 3] = v.w;
    }

    float ymin = INFINITY;
    int   kmin = 0, hsel = 0;

    for (int k = 0; k < KG; ++k) {
        float gm = -INFINITY;
        int   hm = 0;
        // unroll 2 h-iterations: two independent 64-FMA chains for ILP
#pragma unroll 2
        for (int h = 0; h < HKC; ++h) {
            const float* wp = w + (size_t)(k * HKC + h) * NF;
            float acc = t[k * HKC + h];
#pragma unroll
            for (int i = 0; i < NF; ++i) acc = fmaf(wp[i], xr[i], acc);
            // strict > keeps the FIRST max index (jnp.argmax semantics)
            if (acc > gm) { gm = acc; hm = h; }
        }
        // strict < keeps the FIRST min index (jnp.argmin semantics)
        if (gm < ymin) { ymin = gm; kmin = k; hsel = hm; }
    }

    y[n] = ymin;
    atomicAdd(&A[kmin * HKC + hsel], 1.0f);  // device-scope by default
}

extern "C" void kernel_launch(void* const* d_in, const int* in_sizes, int n_in,
                              void* d_out, int out_size, void* d_ws, size_t ws_size,
                              hipStream_t stream) {
    const float* x = (const float*)d_in[0];  // [NS, NF]
    const float* z = (const float*)d_in[1];  // [KG, HKC, NF]
    const float* t = (const float*)d_in[2];  // [KG, HKC]

    float* y = (float*)d_out;        // [NS]
    float* A = (float*)d_out + NS;   // [KG*HKC]
    float* w = (float*)d_ws;         // [KG*HKC*NF] = 128 KB scratch

    int prep_elems = KG * HKC * NF;
    prep_kernel<<<(prep_elems + 255) / 256, 256, 0, stream>>>(z, w, A);

    monn_kernel<<<(NS + 255) / 256, 256, 0, stream>>>(x, w, t, y, A);
}

// Round 2
// 668.103 us; speedup vs baseline: 1.2904x; 1.2904x over previous
//
#include <hip/hip_runtime.h>
#include <math.h>

// Problem constants: N=500000, NFEAT=64, K=8, HK=64
constexpr int NS  = 500000;
constexpr int NF  = 64;
constexpr int KG  = 8;
constexpr int HKC = 64;

typedef __attribute__((ext_vector_type(8))) _Float16 half8;
typedef __attribute__((ext_vector_type(4))) float f32x4;

// Kernel 1: w = exp(z) (fp32) split into fp16 hi/lo pair; zero the A region.
__global__ void prep_kernel(const float* __restrict__ z,
                            _Float16* __restrict__ w_hi,
                            _Float16* __restrict__ w_lo,
                            float* __restrict__ A) {
    int i = blockIdx.x * blockDim.x + threadIdx.x;
    if (i < KG * HKC * NF) {
        float w = expf(z[i]);
        _Float16 h = (_Float16)w;           // RNE
        w_hi[i] = h;
        w_lo[i] = (_Float16)(w - (float)h); // residual: ~2^-22 total pair error
    }
    if (i < KG * HKC) A[i] = 0.0f;
}

// Main kernel: one wave handles 32 rows (2 MFMA row-tiles), all 512 cols.
// Groups processed sequentially -> only 32 acc VGPRs live at a time.
// Fragment layouts (measured, learn_hip m89/m120):
//   A: A[m = lane&15][k = (lane>>4)*8 + j]   (w is [col][k] = B^T, loads identically)
//   C: col = lane&15, row = (lane>>4)*4 + reg
__global__ __launch_bounds__(256, 4) void monn_mfma_kernel(
    const float* __restrict__ x,
    const _Float16* __restrict__ w_hi,
    const _Float16* __restrict__ w_lo,
    const float* __restrict__ t,
    float* __restrict__ y,
    float* __restrict__ A) {

    const int lane = threadIdx.x & 63;
    const int wave = blockIdx.x * 4 + (threadIdx.x >> 6);
    const int base = wave * 32;
    if (base >= NS) return;           // whole-wave exit (500000/32 = 15625 exact)

    const int m = lane & 15;
    const int q = lane >> 4;

    // --- Load x rows and split to fp16 hi/lo fragments (x read exactly once) ---
    half8 Ah[2][2], Al[2][2];
#pragma unroll
    for (int rt = 0; rt < 2; ++rt) {
        const float* xp = x + (size_t)(base + rt * 16 + m) * NF;
#pragma unroll
        for (int s = 0; s < 2; ++s) {
            const int k0 = s * 32 + q * 8;
            const float4 v0 = *reinterpret_cast<const float4*>(xp + k0);
            const float4 v1 = *reinterpret_cast<const float4*>(xp + k0 + 4);
            const float xv[8] = {v0.x, v0.y, v0.z, v0.w, v1.x, v1.y, v1.z, v1.w};
#pragma unroll
            for (int j = 0; j < 8; ++j) {
                _Float16 h = (_Float16)xv[j];
                Ah[rt][s][j] = h;
                Al[rt][s][j] = (_Float16)(xv[j] - (float)h);
            }
        }
    }

    float ymin[2][4];
    int   code[2][4];
#pragma unroll
    for (int rt = 0; rt < 2; ++rt)
#pragma unroll
        for (int j = 0; j < 4; ++j) { ymin[rt][j] = INFINITY; code[rt][j] = 0; }

    for (int g = 0; g < KG; ++g) {
        f32x4 acc[2][4];
        // fold bias t into accumulator init: all 4 regs of a lane share col c*16+m
#pragma unroll
        for (int c = 0; c < 4; ++c) {
            const float tv = t[g * HKC + c * 16 + m];
            acc[0][c] = (f32x4){tv, tv, tv, tv};
            acc[1][c] = acc[0][c];
        }
#pragma unroll
        for (int c = 0; c < 4; ++c) {
            const _Float16* bph = w_hi + (size_t)(g * HKC + c * 16 + m) * NF;
            const _Float16* bpl = w_lo + (size_t)(g * HKC + c * 16 + m) * NF;
#pragma unroll
            for (int s = 0; s < 2; ++s) {
                const half8 Bh = *reinterpret_cast<const half8*>(bph + s * 32 + q * 8);
                const half8 Bl = *reinterpret_cast<const half8*>(bpl + s * 32 + q * 8);
#pragma unroll
                for (int rt = 0; rt < 2; ++rt) {
                    acc[rt][c] = __builtin_amdgcn_mfma_f32_16x16x32_f16(Ah[rt][s], Bh, acc[rt][c], 0, 0, 0);
                    acc[rt][c] = __builtin_amdgcn_mfma_f32_16x16x32_f16(Al[rt][s], Bh, acc[rt][c], 0, 0, 0);
                    acc[rt][c] = __builtin_amdgcn_mfma_f32_16x16x32_f16(Ah[rt][s], Bl, acc[rt][c], 0, 0, 0);
                }
            }
        }

        // --- epilogue: per row, argmax over this group's 64 cols, then running min ---
#pragma unroll
        for (int rt = 0; rt < 2; ++rt) {
#pragma unroll
            for (int j = 0; j < 4; ++j) {
                float v = acc[rt][0][j];
                int   h = m;
                // in-lane over c: ascending h, strict > keeps first occurrence
#pragma unroll
                for (int c = 1; c < 4; ++c) {
                    const float vc = acc[rt][c][j];
                    if (vc > v) { v = vc; h = c * 16 + m; }
                }
                // butterfly over the 16 col-lanes (xor bits 0..3 stay in-quadgroup)
#pragma unroll
                for (int off = 1; off < 16; off <<= 1) {
                    const float v2 = __shfl_xor(v, off);
                    const int   h2 = __shfl_xor(h, off);
                    if (v2 > v || (v2 == v && h2 < h)) { v = v2; h = h2; }
                }
                // running min over groups: strict < keeps first (lowest g)
                if (v < ymin[rt][j]) { ymin[rt][j] = v; code[rt][j] = g * HKC + h; }
            }
        }
    }

    // one lane per 4 rows writes y and bumps the histogram
    if (m == 0) {
#pragma unroll
        for (int rt = 0; rt < 2; ++rt)
#pragma unroll
            for (int j = 0; j < 4; ++j) {
                const int row = base + rt * 16 + q * 4 + j;
                y[row] = ymin[rt][j];
                atomicAdd(&A[code[rt][j]], 1.0f);  // device-scope by default
            }
    }
}

extern "C" void kernel_launch(void* const* d_in, const int* in_sizes, int n_in,
                              void* d_out, int out_size, void* d_ws, size_t ws_size,
                              hipStream_t stream) {
    const float* x = (const float*)d_in[0];  // [NS, NF]
    const float* z = (const float*)d_in[1];  // [KG, HKC, NF]
    const float* t = (const float*)d_in[2];  // [KG, HKC]

    float* y = (float*)d_out;        // [NS]
    float* A = (float*)d_out + NS;   // [KG*HKC]

    _Float16* w_hi = (_Float16*)d_ws;                 // 64 KB
    _Float16* w_lo = w_hi + (size_t)KG * HKC * NF;    // 64 KB

    const int prep_elems = KG * HKC * NF;
    prep_kernel<<<(prep_elems + 255) / 256, 256, 0, stream>>>(z, w_hi, w_lo, A);

    const int waves = NS / 32;                  // 15625
    const int blocks = (waves + 3) / 4;         // 3907
    monn_mfma_kernel<<<blocks, 256, 0, stream>>>(x, w_hi, w_lo, t, y, A);
}